// Round 3
// baseline (268.706 us; speedup 1.0000x reference)
//
#include <hip/hip_runtime.h>
#include <hip/hip_bf16.h>
#include <math.h>

// ip (8, 256, 128, 128) fp32 -> DCT-III along channels:
// out[b,c,p] = ip[b,0,p] + 2*sum_{k>0} ip[b,k,p] * cos(pi*k*(2c+1)/512)
#define NB   8
#define NC   256
#define NHW  (128 * 128)

// Block: full c (256) x 64 p, full K=256 staged ONCE into LDS (32 KB bf16).
// 512 threads = 8 waves (4 c-quarters x 2 p-halves), per-wave 64c x 32p.
#define BN 64

typedef __attribute__((ext_vector_type(4))) float f32x4;
typedef __attribute__((ext_vector_type(8))) short bf16x8;

__device__ __forceinline__ unsigned f2bf_lo(float f) {
    unsigned u = __builtin_bit_cast(unsigned, f);
    u += 0x7fffu + ((u >> 16) & 1u);
    return u >> 16;
}
__device__ __forceinline__ unsigned f2bf_hi(float f) {
    unsigned u = __builtin_bit_cast(unsigned, f);
    u += 0x7fffu + ((u >> 16) & 1u);
    return u & 0xffff0000u;
}

// DCT-III coefficient matrix, bf16 row-major [c][k], exact int angle reduction.
__global__ void coef_kernel(unsigned short* __restrict__ coef) {
    int idx = blockIdx.x * 256 + threadIdx.x;
    int c = idx >> 8;
    int k = idx & 255;
    int t = (k * (2 * c + 1)) & 1023;
    float v = (k == 0) ? 1.0f : 2.0f * cosf((float)t * (float)(M_PI / 512.0));
    coef[idx] = (unsigned short)f2bf_lo(v);
}

// LDS layout: Xlds[p][k] bf16, row = p (64 rows x 512 B), k in chunks of 8
// (16 B). Chunk index XOR-swizzled with (row & 7): both the staging
// ds_write_b128 (8 consecutive lanes = 8 consecutive rows, same chunk) and the
// fragment ds_read_b128 (8 consecutive lanes = 8 consecutive rows, same chunk)
// hit 8 distinct bank-quads -> conflict-free, no padding.
__device__ __forceinline__ int swz_off(int row, int chunk) {
    return row * 512 + ((chunk ^ (row & 7)) << 4);
}

__global__ __launch_bounds__(512, 4)
void dct_gemm(const float* __restrict__ X, const unsigned short* __restrict__ Mcoef,
              float* __restrict__ Out) {
    __shared__ unsigned char Xlds[BN * 512];   // 32 KB

    const int tid  = threadIdx.x;
    const int lane = tid & 63;
    const int wave = tid >> 6;        // 0..7
    const int wm   = wave >> 1;       // 0..3 -> c quarter (64 rows)
    const int wn   = wave & 1;        // 0..1 -> p half (32 cols)
    const int m16  = lane & 15;
    const int quad = lane >> 4;

    const int p0 = blockIdx.x * BN;
    const float* Xb = X + (size_t)blockIdx.y * (NC * NHW);
    float* Ob = Out + (size_t)blockIdx.y * (NC * NHW);

    // ---- stage full X tile (64p x 256k) in ONE shot ----
    // thread: p = sr, k = sh*32 .. +31  (global loads coalesced across lanes)
    const int sr = tid & 63;
    const int sh = tid >> 6;
    const float* xsrc = Xb + (size_t)(sh * 32) * NHW + p0 + sr;

#pragma unroll
    for (int half = 0; half < 2; ++half) {
        float v[16];
#pragma unroll
        for (int j = 0; j < 16; j++) v[j] = xsrc[(half * 16 + j) * NHW];
#pragma unroll
        for (int cc = 0; cc < 2; cc++) {          // two 8-k chunks of 16 B
            int chunk = sh * 4 + half * 2 + cc;
            int pk[4];
#pragma unroll
            for (int q = 0; q < 4; q++)
                pk[q] = (int)(f2bf_lo(v[cc * 8 + 2 * q]) | f2bf_hi(v[cc * 8 + 2 * q + 1]));
            *(int4*)(Xlds + swz_off(sr, chunk)) = (int4){pk[0], pk[1], pk[2], pk[3]};
        }
    }
    __syncthreads();   // the only barrier

    // ---- compute: 8 k-steps, A from global (M is 128 KB, L2-hot) ----
    f32x4 acc[4][2];
#pragma unroll
    for (int i = 0; i < 4; i++)
#pragma unroll
        for (int j = 0; j < 2; j++) acc[i][j] = (f32x4){0.f, 0.f, 0.f, 0.f};

    const unsigned short* Abase = Mcoef + (wm * 64 + m16) * NC + quad * 8;
    const int brow0 = wn * 32 + m16;

#pragma unroll
    for (int s = 0; s < 8; ++s) {
        bf16x8 afr[4], bfr[2];
#pragma unroll
        for (int mt = 0; mt < 4; mt++)
            afr[mt] = *(const bf16x8*)(Abase + mt * 16 * NC + s * 32);
#pragma unroll
        for (int nt = 0; nt < 2; nt++)
            bfr[nt] = *(const bf16x8*)(Xlds + swz_off(brow0 + nt * 16, s * 4 + quad));
#pragma unroll
        for (int mt = 0; mt < 4; mt++)
#pragma unroll
            for (int nt = 0; nt < 2; nt++)
                acc[mt][nt] = __builtin_amdgcn_mfma_f32_16x16x32_bf16(
                    afr[mt], bfr[nt], acc[mt][nt], 0, 0, 0);
    }

    // ---- epilogue: D layout col = lane&15 (p), row = quad*4 + r (c) ----
#pragma unroll
    for (int mt = 0; mt < 4; mt++) {
#pragma unroll
        for (int nt = 0; nt < 2; nt++) {
            int cc = wm * 64 + mt * 16 + quad * 4;
            int pp = p0 + wn * 32 + nt * 16 + m16;
            float* o = Ob + cc * NHW + pp;
#pragma unroll
            for (int r = 0; r < 4; r++)
                o[r * NHW] = acc[mt][nt][r];
        }
    }
}

extern "C" void kernel_launch(void* const* d_in, const int* in_sizes, int n_in,
                              void* d_out, int out_size, void* d_ws, size_t ws_size,
                              hipStream_t stream) {
    const float* ip = (const float*)d_in[0];
    float* out = (float*)d_out;
    unsigned short* coef = (unsigned short*)d_ws;   // 128 KB scratch (re-poisoned each launch)

    coef_kernel<<<dim3(256), dim3(256), 0, stream>>>(coef);

    dim3 grid(NHW / BN, NB);   // (256, 8) = 2048 blocks x 512 threads
    dct_gemm<<<grid, dim3(512), 0, stream>>>(ip, coef, out);
}